// Round 3
// baseline (111.132 us; speedup 1.0000x reference)
//
#include <hip/hip_runtime.h>

typedef __attribute__((ext_vector_type(8))) _Float16 f16x8;
typedef __attribute__((ext_vector_type(4))) _Float16 f16x4;
typedef __attribute__((ext_vector_type(4))) float   f32x4;

#define BATCH 16384
#define NFEAT 512
#define NCLS  1000
#define NLEAF 256
#define NINT  255
#define NPAD  1024
#define LDP   72   // padded LDS row stride (f16): 144B -> 2-way bank alias (free)

// ---- convert gate_w (255x512) -> f16 padded to 256x512 (row 255 = 0) ----
__global__ __launch_bounds__(256) void cvt_gw(const float4* __restrict__ in,
                                              f16x4* __restrict__ out) {
  int i = blockIdx.x * 256 + threadIdx.x;   // quad index, 32768 total
  int row = i >> 7;                          // 128 quads per row
  f16x4 o;
  if (row < NINT) {
    float4 v = in[i];
    o[0] = (_Float16)v.x; o[1] = (_Float16)v.y;
    o[2] = (_Float16)v.z; o[3] = (_Float16)v.w;
  } else {
    o[0] = o[1] = o[2] = o[3] = (_Float16)0.f;
  }
  out[i] = o;
}

// ---- softmax rows of leaf_logits (256x1000) -> distT[c][l] f16, rows 1000..1023 zeroed ----
__global__ __launch_bounds__(256) void softmax_t(const float* __restrict__ L,
                                                 _Float16* __restrict__ distT) {
  __shared__ float red[4];
  const int l = blockIdx.x, t = threadIdx.x;
  const int wave = t >> 6, lane = t & 63;
  float v[4];
  if (t < 250) {
    float4 f = *(const float4*)&L[(size_t)l * NCLS + t * 4];
    v[0] = f.x; v[1] = f.y; v[2] = f.z; v[3] = f.w;
  } else {
    v[0] = v[1] = v[2] = v[3] = -1e30f;
  }
  float mx = fmaxf(fmaxf(v[0], v[1]), fmaxf(v[2], v[3]));
#pragma unroll
  for (int s = 32; s; s >>= 1) mx = fmaxf(mx, __shfl_xor(mx, s));
  if (lane == 0) red[wave] = mx;
  __syncthreads();
  mx = fmaxf(fmaxf(red[0], red[1]), fmaxf(red[2], red[3]));
  __syncthreads();
  float e[4], sum = 0.f;
#pragma unroll
  for (int i = 0; i < 4; ++i) { e[i] = __expf(v[i] - mx); sum += e[i]; }
  if (t >= 250) { e[0] = e[1] = e[2] = e[3] = 0.f; sum = 0.f; }
#pragma unroll
  for (int s = 32; s; s >>= 1) sum += __shfl_xor(sum, s);
  if (lane == 0) red[wave] = sum;
  __syncthreads();
  sum = red[0] + red[1] + red[2] + red[3];
  float inv = 1.f / sum;
  if (t < 250) {
#pragma unroll
    for (int i = 0; i < 4; ++i)
      distT[(size_t)(t * 4 + i) * NLEAF + l] = (_Float16)(e[i] * inv);
  }
  if (t < NPAD - NCLS) distT[(size_t)(NCLS + t) * NLEAF + l] = (_Float16)0.f;
}

// ---- fused: gates = sigmoid(x @ gwh^T + b); mu = tree-product -> f16 ----
// BM=32 rows/block, BN=256 (all nodes), K=512, BK=64. 512 threads = 8 waves (2x4).
__global__ __launch_bounds__(512)
void gate_mu(const float* __restrict__ x, const _Float16* __restrict__ gwh,
             const float* __restrict__ gb, _Float16* __restrict__ mu) {
  __shared__ union {
    struct { _Float16 A[32 * LDP]; _Float16 B[256 * LDP]; } s;  // 41,472 B
    float P[32 * 256];                                          // 32,768 B
  } sm;
  const int tid = threadIdx.x;
  const int wave = tid >> 6, lane = tid & 63;
  const int ln15 = lane & 15, lhi = lane >> 4;
  const int wr = wave >> 2, wc = wave & 3;          // 2 x 4 waves, 16r x 64c each
  const int r0 = blockIdx.x * 32;

  f32x4 acc[4] = {};

  const int arow = tid >> 4, acol = (tid & 15) * 4;  // A: 32 rows x 16 float4 (1/thread)
  const int brow0 = tid >> 3, bcol = (tid & 7) * 8;  // B: 4 chunks of 64 rows x 8 uint4

  float4 pa;
  uint4  pb[4];

#define LOAD_AB(k0)                                                            \
  {                                                                            \
    pa = *(const float4*)&x[(size_t)(r0 + arow) * NFEAT + (k0) + acol];        \
    _Pragma("unroll")                                                          \
    for (int i = 0; i < 4; ++i)                                                \
      pb[i] = *(const uint4*)&gwh[(size_t)(i * 64 + brow0) * NFEAT + (k0) + bcol]; \
  }
#define WRITE_AB()                                                             \
  {                                                                            \
    f16x4 h;                                                                   \
    h[0] = (_Float16)pa.x; h[1] = (_Float16)pa.y;                              \
    h[2] = (_Float16)pa.z; h[3] = (_Float16)pa.w;                              \
    *(f16x4*)&sm.s.A[arow * LDP + acol] = h;                                   \
    _Pragma("unroll")                                                          \
    for (int i = 0; i < 4; ++i)                                                \
      *(uint4*)&sm.s.B[(i * 64 + brow0) * LDP + bcol] = pb[i];                 \
  }

  LOAD_AB(0);
  WRITE_AB();
  __syncthreads();

  for (int k = 0; k < NFEAT / 64; ++k) {
    if (k < NFEAT / 64 - 1) LOAD_AB((k + 1) * 64);
#pragma unroll
    for (int kk = 0; kk < 2; ++kk) {
      f16x8 a, b[4];
      a = *(const f16x8*)&sm.s.A[(wr * 16 + ln15) * LDP + kk * 32 + lhi * 8];
#pragma unroll
      for (int n = 0; n < 4; ++n)
        b[n] = *(const f16x8*)&sm.s.B[(wc * 64 + n * 16 + ln15) * LDP + kk * 32 + lhi * 8];
#pragma unroll
      for (int n = 0; n < 4; ++n)
        acc[n] = __builtin_amdgcn_mfma_f32_16x16x32_f16(a, b[n], acc[n], 0, 0, 0);
    }
    __syncthreads();
    if (k < NFEAT / 64 - 1) { WRITE_AB(); __syncthreads(); }
  }

  // epilogue 1: sigmoid -> P in LDS
#pragma unroll
  for (int n = 0; n < 4; ++n) {
    int col = wc * 64 + n * 16 + ln15;
    float bb = (col < NINT) ? gb[col] : 0.f;
#pragma unroll
    for (int j = 0; j < 4; ++j) {
      int rl = wr * 16 + lhi * 4 + j;
      float v = acc[n][j] + bb;
      sm.P[rl * 256 + col] = 1.f / (1.f + __expf(-v));
    }
  }
  __syncthreads();

  // epilogue 2: tree product. wave handles 4 rows; lane handles leaves 4*lane..4*lane+3
  const int lf = lane * 4;
#pragma unroll
  for (int rr = 0; rr < 4; ++rr) {
    int row = wave * 4 + rr;
    const float* p = &sm.P[row * 256];
    float pre = 1.f;
#pragma unroll
    for (int d = 0; d < 6; ++d) {
      int node = (1 << d) - 1 + (lf >> (8 - d));
      int bit  = (lf >> (7 - d)) & 1;
      float g = p[node];
      pre *= bit ? g : (1.f - g);
    }
    float g6  = p[63 + lane];
    float g7a = p[127 + 2 * lane];
    float g7b = p[128 + 2 * lane];
    f16x4 o;
    o[0] = (_Float16)(pre * (1.f - g6) * (1.f - g7a));
    o[1] = (_Float16)(pre * (1.f - g6) * g7a);
    o[2] = (_Float16)(pre * g6 * (1.f - g7b));
    o[3] = (_Float16)(pre * g6 * g7b);
    *(f16x4*)&mu[(size_t)(r0 + row) * 256 + lf] = o;
  }
#undef LOAD_AB
#undef WRITE_AB
}

// ---- gemm2: out = mu(16384x256) @ distT(1024x256)^T, 128x128 tile, BK=64 ----
// grid (8, 128): col-tile fast for mu L2 reuse. LDS-staged coalesced epilogue.
__global__ __launch_bounds__(256)
void gemm2(const _Float16* __restrict__ A, const _Float16* __restrict__ B,
           float* __restrict__ out) {
  __shared__ union {
    struct { _Float16 lA[128 * LDP]; _Float16 lB[128 * LDP]; } s;  // 36,864 B
    float sC[64 * 132];                                            // 33,792 B
  } sm;
  const int tid = threadIdx.x;
  const int wave = tid >> 6, lane = tid & 63;
  const int ln15 = lane & 15, lhi = lane >> 4;
  const int wr = wave >> 1, wc = wave & 1;          // 2x2 waves, 64r x 64c each
  const int c0 = blockIdx.x * 128;
  const int r0 = blockIdx.y * 128;

  f32x4 acc[4][4] = {};

  const int srow = tid >> 3, scol = (tid & 7) * 8;  // per chunk: 32 rows x 8 uint4
  uint4 pa[4], pb[4];

#define G2_LOAD(k0)                                                             \
  {                                                                             \
    _Pragma("unroll")                                                           \
    for (int i = 0; i < 4; ++i) {                                               \
      pa[i] = *(const uint4*)&A[(size_t)(r0 + i * 32 + srow) * 256 + (k0) + scol]; \
      pb[i] = *(const uint4*)&B[(size_t)(c0 + i * 32 + srow) * 256 + (k0) + scol]; \
    }                                                                           \
  }
#define G2_WRITE()                                                              \
  {                                                                             \
    _Pragma("unroll")                                                           \
    for (int i = 0; i < 4; ++i) {                                               \
      *(uint4*)&sm.s.lA[(i * 32 + srow) * LDP + scol] = pa[i];                  \
      *(uint4*)&sm.s.lB[(i * 32 + srow) * LDP + scol] = pb[i];                  \
    }                                                                           \
  }

  G2_LOAD(0);
  G2_WRITE();
  __syncthreads();

  for (int k = 0; k < 4; ++k) {
    if (k < 3) G2_LOAD((k + 1) * 64);
#pragma unroll
    for (int kk = 0; kk < 2; ++kk) {
      f16x8 a[4], b[4];
#pragma unroll
      for (int m = 0; m < 4; ++m)
        a[m] = *(const f16x8*)&sm.s.lA[(wr * 64 + m * 16 + ln15) * LDP + kk * 32 + lhi * 8];
#pragma unroll
      for (int n = 0; n < 4; ++n)
        b[n] = *(const f16x8*)&sm.s.lB[(wc * 64 + n * 16 + ln15) * LDP + kk * 32 + lhi * 8];
#pragma unroll
      for (int m = 0; m < 4; ++m)
#pragma unroll
        for (int n = 0; n < 4; ++n)
          acc[m][n] = __builtin_amdgcn_mfma_f32_16x16x32_f16(a[m], b[n], acc[m][n], 0, 0, 0);
    }
    __syncthreads();
    if (k < 3) { G2_WRITE(); __syncthreads(); }
  }

  // LDS-staged coalesced epilogue: two 64-row chunks
  const int qrow = tid >> 5;   // 0..7
  const int q    = tid & 31;   // float4-quad within 128-col tile
  const int col  = c0 + q * 4;
#pragma unroll
  for (int half = 0; half < 2; ++half) {
    __syncthreads();
    if (wr == half) {
#pragma unroll
      for (int m = 0; m < 4; ++m)
#pragma unroll
        for (int n = 0; n < 4; ++n)
#pragma unroll
          for (int j = 0; j < 4; ++j)
            sm.sC[(m * 16 + lhi * 4 + j) * 132 + wc * 64 + n * 16 + ln15] = acc[m][n][j];
    }
    __syncthreads();
    if (col < NCLS) {
#pragma unroll
      for (int i = 0; i < 8; ++i) {
        int lrow = qrow + i * 8;
        float4 v = *(const float4*)&sm.sC[lrow * 132 + q * 4];
        *(float4*)&out[(size_t)(r0 + half * 64 + lrow) * NCLS + col] = v;
      }
    }
  }
#undef G2_LOAD
#undef G2_WRITE
}

extern "C" void kernel_launch(void* const* d_in, const int* in_sizes, int n_in,
                              void* d_out, int out_size, void* d_ws, size_t ws_size,
                              hipStream_t stream) {
  const float* x  = (const float*)d_in[0];   // 16384x512
  const float* gw = (const float*)d_in[1];   // 255x512
  const float* gb = (const float*)d_in[2];   // 255
  const float* ll = (const float*)d_in[3];   // 256x1000
  float* out = (float*)d_out;                // 16384x1000
  char* ws = (char*)d_ws;

  _Float16* gwh   = (_Float16*)(ws);                 // 262,144 B
  _Float16* distT = (_Float16*)(ws + 262144);        // 524,288 B
  _Float16* mu    = (_Float16*)(ws + 786432);        // 8,388,608 B

  cvt_gw   <<<128, 256, 0, stream>>>((const float4*)gw, (f16x4*)gwh);
  softmax_t<<<256, 256, 0, stream>>>(ll, distT);
  gate_mu  <<<BATCH / 32, 512, 0, stream>>>(x, gwh, gb, mu);
  gemm2    <<<dim3(NPAD / 128, BATCH / 128), 256, 0, stream>>>(mu, distT, out);
}

// Round 4
// 99.570 us; speedup vs baseline: 1.1161x; 1.1161x over previous
//
#include <hip/hip_runtime.h>

typedef __attribute__((ext_vector_type(8))) _Float16 f16x8;
typedef __attribute__((ext_vector_type(4))) _Float16 f16x4;
typedef __attribute__((ext_vector_type(4))) float   f32x4;

#define BATCH 16384
#define NFEAT 512
#define NCLS  1000
#define NLEAF 256
#define NINT  255
#define NPAD  1024
#define LDP   72    // phase-1 LDS row stride (f16): 144B, (144/16)%8 odd -> conflict floor
#define MUP   264   // mu LDS row stride (f16): 528B, (528/16)%8 odd -> conflict floor

// ---- convert gate_w (255x512) -> f16 padded to 256x512 (row 255 = 0) ----
__global__ __launch_bounds__(256) void cvt_gw(const float4* __restrict__ in,
                                              f16x4* __restrict__ out) {
  int i = blockIdx.x * 256 + threadIdx.x;   // quad index, 32768 total
  int row = i >> 7;
  f16x4 o;
  if (row < NINT) {
    float4 v = in[i];
    o[0] = (_Float16)v.x; o[1] = (_Float16)v.y;
    o[2] = (_Float16)v.z; o[3] = (_Float16)v.w;
  } else {
    o[0] = o[1] = o[2] = o[3] = (_Float16)0.f;
  }
  out[i] = o;
}

// ---- softmax rows of leaf_logits (256x1000) -> distT[c][l] f16, rows 1000..1023 zeroed ----
__global__ __launch_bounds__(256) void softmax_t(const float* __restrict__ L,
                                                 _Float16* __restrict__ distT) {
  __shared__ float red[4];
  const int l = blockIdx.x, t = threadIdx.x;
  const int wave = t >> 6, lane = t & 63;
  float v[4];
  if (t < 250) {
    float4 f = *(const float4*)&L[(size_t)l * NCLS + t * 4];
    v[0] = f.x; v[1] = f.y; v[2] = f.z; v[3] = f.w;
  } else {
    v[0] = v[1] = v[2] = v[3] = -1e30f;
  }
  float mx = fmaxf(fmaxf(v[0], v[1]), fmaxf(v[2], v[3]));
#pragma unroll
  for (int s = 32; s; s >>= 1) mx = fmaxf(mx, __shfl_xor(mx, s));
  if (lane == 0) red[wave] = mx;
  __syncthreads();
  mx = fmaxf(fmaxf(red[0], red[1]), fmaxf(red[2], red[3]));
  __syncthreads();
  float e[4], sum = 0.f;
#pragma unroll
  for (int i = 0; i < 4; ++i) { e[i] = __expf(v[i] - mx); sum += e[i]; }
  if (t >= 250) { e[0] = e[1] = e[2] = e[3] = 0.f; sum = 0.f; }
#pragma unroll
  for (int s = 32; s; s >>= 1) sum += __shfl_xor(sum, s);
  if (lane == 0) red[wave] = sum;
  __syncthreads();
  sum = red[0] + red[1] + red[2] + red[3];
  float inv = 1.f / sum;
  if (t < 250) {
#pragma unroll
    for (int i = 0; i < 4; ++i)
      distT[(size_t)(t * 4 + i) * NLEAF + l] = (_Float16)(e[i] * inv);
  }
  if (t < NPAD - NCLS) distT[(size_t)(NCLS + t) * NLEAF + l] = (_Float16)0.f;
}

// ---- fused: gemm1 + sigmoid + tree-product + gemm2, 64 rows/block, 256 blocks ----
__global__ __launch_bounds__(512)
void fused(const float* __restrict__ x, const _Float16* __restrict__ gwh,
           const float* __restrict__ gb, const _Float16* __restrict__ distT,
           float* __restrict__ out) {
  __shared__ union {
    struct { _Float16 A[64 * LDP]; _Float16 B[256 * LDP]; } s;  // 46,080 B
    float P[64 * 256];                                          // 65,536 B
  } sm;
  __shared__ _Float16 sMu[64 * MUP];                            // 33,792 B

  const int tid  = threadIdx.x;
  const int wave = tid >> 6, lane = tid & 63;
  const int ln15 = lane & 15, lhi = lane >> 4;
  const int wr = wave >> 2, wc = wave & 3;      // phase1: 2x4 waves, 32r x 64c
  const int r0 = blockIdx.x * 64;

  // preload bias for phase-1 epilogue (overlaps staging latency)
  float bias_[4];
#pragma unroll
  for (int n = 0; n < 4; ++n) {
    int col = wc * 64 + n * 16 + ln15;
    bias_[n] = (col < NINT) ? gb[col] : 0.f;
  }

  // ---------------- phase 1: logits = x @ gwh^T ----------------
  f32x4 acc1[2][4] = {};
  const int arow = tid >> 4, acol = (tid & 15) * 4;  // A: 2 float4/thread
  const int brow = tid >> 3, bcol = (tid & 7) * 8;   // B: 4 uint4/thread

  float4 pa, pa2;
  uint4  pb[4];

#define P1_LOAD(k0)                                                              \
  {                                                                              \
    pa  = *(const float4*)&x[(size_t)(r0 + arow) * NFEAT + (k0) + acol];         \
    pa2 = *(const float4*)&x[(size_t)(r0 + 32 + arow) * NFEAT + (k0) + acol];    \
    _Pragma("unroll")                                                            \
    for (int i = 0; i < 4; ++i)                                                  \
      pb[i] = *(const uint4*)&gwh[(size_t)(i * 64 + brow) * NFEAT + (k0) + bcol];\
  }
#define P1_WRITE()                                                               \
  {                                                                              \
    f16x4 h;                                                                     \
    h[0] = (_Float16)pa.x; h[1] = (_Float16)pa.y;                                \
    h[2] = (_Float16)pa.z; h[3] = (_Float16)pa.w;                                \
    *(f16x4*)&sm.s.A[arow * LDP + acol] = h;                                     \
    h[0] = (_Float16)pa2.x; h[1] = (_Float16)pa2.y;                              \
    h[2] = (_Float16)pa2.z; h[3] = (_Float16)pa2.w;                              \
    *(f16x4*)&sm.s.A[(32 + arow) * LDP + acol] = h;                              \
    _Pragma("unroll")                                                            \
    for (int i = 0; i < 4; ++i)                                                  \
      *(uint4*)&sm.s.B[(i * 64 + brow) * LDP + bcol] = pb[i];                    \
  }

  P1_LOAD(0);
  for (int k = 0; k < NFEAT / 64; ++k) {
    P1_WRITE();                      // waits on in-flight loads (vmcnt)
    __syncthreads();
    if (k < NFEAT / 64 - 1) P1_LOAD((k + 1) * 64);   // next loads fly over MFMA
#pragma unroll
    for (int kk = 0; kk < 2; ++kk) {
      f16x8 a[2], b[4];
#pragma unroll
      for (int m = 0; m < 2; ++m)
        a[m] = *(const f16x8*)&sm.s.A[(wr * 32 + m * 16 + ln15) * LDP + kk * 32 + lhi * 8];
#pragma unroll
      for (int n = 0; n < 4; ++n)
        b[n] = *(const f16x8*)&sm.s.B[(wc * 64 + n * 16 + ln15) * LDP + kk * 32 + lhi * 8];
#pragma unroll
      for (int m = 0; m < 2; ++m)
#pragma unroll
        for (int n = 0; n < 4; ++n)
          acc1[m][n] = __builtin_amdgcn_mfma_f32_16x16x32_f16(a[m], b[n], acc1[m][n], 0, 0, 0);
    }
    __syncthreads();                 // LDS reads done before next overwrite
  }

  // ---------------- phase 2a: sigmoid -> P (LDS, overlays staging) ----------------
#pragma unroll
  for (int m = 0; m < 2; ++m)
#pragma unroll
    for (int n = 0; n < 4; ++n) {
      int col = wc * 64 + n * 16 + ln15;
#pragma unroll
      for (int j = 0; j < 4; ++j) {
        int rl = wr * 32 + m * 16 + lhi * 4 + j;
        float v = acc1[m][n][j] + bias_[n];
        sm.P[rl * 256 + col] = 1.f / (1.f + __expf(-v));
      }
    }
  __syncthreads();

  // ---------------- phase 2b: tree product -> sMu ----------------
  const int lf = lane * 4;
#pragma unroll
  for (int rr = 0; rr < 8; ++rr) {
    int row = wave * 8 + rr;
    const float* p = &sm.P[row * 256];
    float pre = 1.f;
#pragma unroll
    for (int d = 0; d < 6; ++d) {
      int node = (1 << d) - 1 + (lf >> (8 - d));
      int bit  = (lf >> (7 - d)) & 1;
      float g = p[node];
      pre *= bit ? g : (1.f - g);
    }
    float g6  = p[63 + lane];
    float g7a = p[127 + 2 * lane];
    float g7b = p[128 + 2 * lane];
    f16x4 o;
    o[0] = (_Float16)(pre * (1.f - g6) * (1.f - g7a));
    o[1] = (_Float16)(pre * (1.f - g6) * g7a);
    o[2] = (_Float16)(pre * g6 * (1.f - g7b));
    o[3] = (_Float16)(pre * g6 * g7b);
    *(f16x4*)&sMu[row * MUP + lf] = o;
  }
  __syncthreads();

  // ---------------- phase 3: out = mu @ distT^T, distT in registers ----------------
  const int wr2 = wave >> 2, wc2 = wave & 3;    // 2x4 waves, 32r x 32c per wave
  for (int ct = 0; ct < 8; ++ct) {
    const int c0 = ct * 128 + wc2 * 32;
    // B fragments for this col-tile: 2 class-groups x 8 k-steps, straight from L2
    f16x8 bb0[8], bb1[8];
#pragma unroll
    for (int kk = 0; kk < 8; ++kk) {
      bb0[kk] = *(const f16x8*)&distT[(size_t)(c0 + ln15) * NLEAF + kk * 32 + lhi * 8];
      bb1[kk] = *(const f16x8*)&distT[(size_t)(c0 + 16 + ln15) * NLEAF + kk * 32 + lhi * 8];
    }
    f32x4 a00 = {}, a01 = {}, a10 = {}, a11 = {};
#pragma unroll
    for (int kk = 0; kk < 8; ++kk) {
      f16x8 a0 = *(const f16x8*)&sMu[(wr2 * 32 + ln15) * MUP + kk * 32 + lhi * 8];
      f16x8 a1 = *(const f16x8*)&sMu[(wr2 * 32 + 16 + ln15) * MUP + kk * 32 + lhi * 8];
      a00 = __builtin_amdgcn_mfma_f32_16x16x32_f16(a0, bb0[kk], a00, 0, 0, 0);
      a01 = __builtin_amdgcn_mfma_f32_16x16x32_f16(a0, bb1[kk], a01, 0, 0, 0);
      a10 = __builtin_amdgcn_mfma_f32_16x16x32_f16(a1, bb0[kk], a10, 0, 0, 0);
      a11 = __builtin_amdgcn_mfma_f32_16x16x32_f16(a1, bb1[kk], a11, 0, 0, 0);
    }
    // direct stores (64B segments per 16-lane group)
    int col0 = c0 + ln15;
    int col1 = c0 + 16 + ln15;
    int rbase = r0 + wr2 * 32 + lhi * 4;
    if (col0 < NCLS) {
#pragma unroll
      for (int j = 0; j < 4; ++j) {
        out[(size_t)(rbase + j) * NCLS + col0]      = a00[j];
        out[(size_t)(rbase + 16 + j) * NCLS + col0] = a10[j];
      }
    }
    if (col1 < NCLS) {
#pragma unroll
      for (int j = 0; j < 4; ++j) {
        out[(size_t)(rbase + j) * NCLS + col1]      = a01[j];
        out[(size_t)(rbase + 16 + j) * NCLS + col1] = a11[j];
      }
    }
  }
#undef P1_LOAD
#undef P1_WRITE
}

extern "C" void kernel_launch(void* const* d_in, const int* in_sizes, int n_in,
                              void* d_out, int out_size, void* d_ws, size_t ws_size,
                              hipStream_t stream) {
  const float* x  = (const float*)d_in[0];   // 16384x512
  const float* gw = (const float*)d_in[1];   // 255x512
  const float* gb = (const float*)d_in[2];   // 255
  const float* ll = (const float*)d_in[3];   // 256x1000
  float* out = (float*)d_out;                // 16384x1000
  char* ws = (char*)d_ws;

  _Float16* gwh   = (_Float16*)(ws);            // 262,144 B
  _Float16* distT = (_Float16*)(ws + 262144);   // 524,288 B

  cvt_gw   <<<128, 256, 0, stream>>>((const float4*)gw, (f16x4*)gwh);
  softmax_t<<<256, 256, 0, stream>>>(ll, distT);
  fused    <<<BATCH / 64, 512, 0, stream>>>(x, gwh, gb, distT, out);
}